// Round 14
// baseline (218.374 us; speedup 1.0000x reference)
//
#include <hip/hip_runtime.h>
#include <hip/hip_bf16.h>
#include <float.h>

#define F_DIM 64
#define H_DIM 128
#define LW2   104   // wt2 row stride (bf16) for K=96 [x[e0]|ppf|pad]: 208 B, 16B-aligned
#define LW1   72    // w1t row stride (bf16) for K=64 [x[e1]]: 144 B, 16B-aligned
#define NB    128   // histogram blocks (counting-sort partitions)
#define SMAX  25600 // max slots supported by the LDS histogram (100 KB of 160 KB/CU)

typedef __attribute__((ext_vector_type(8))) short short8;   // 8 bf16 (mfma A/B frag)
typedef __attribute__((ext_vector_type(4))) float f32x4;    // mfma C/D frag

__device__ __forceinline__ unsigned short f2bf(float f) {
    __hip_bfloat16 h = __float2bfloat16(f);
    return __builtin_bit_cast(unsigned short, h);
}
__device__ __forceinline__ unsigned pk(float a, float b) {
    return (unsigned)f2bf(a) | ((unsigned)f2bf(b) << 16);
}

__device__ __forceinline__ float angle3(float ax, float ay, float az,
                                        float bx, float by, float bz) {
    float cx = ay*bz - az*by;
    float cy = az*bx - ax*bz;
    float cz = ax*by - ay*bx;
    float cn = sqrtf(cx*cx + cy*cy + cz*cz);
    float d  = ax*bx + ay*by + az*bz;
    return atan2f(cn, d);
}

// pure streaming pass, ZERO atomics: wt2 + w1t builds, xbf (x->bf16 mfma layout),
// pn (packed pos+normal, 32B/node -> 1 cache line per node gather in place_kernel),
// node2slot scatter, pos tail.
__global__ __launch_bounds__(256)
void prep0(const float* __restrict__ W, unsigned short* __restrict__ wt2,
           unsigned short* __restrict__ w1t, const float* __restrict__ x,
           unsigned short* __restrict__ xbf, const int* __restrict__ idx,
           int* __restrict__ node2slot, const float* __restrict__ pos,
           const float* __restrict__ normal, float* __restrict__ pn,
           float* __restrict__ out, int N, int S, int NF8) {
    const int T = gridDim.x * blockDim.x;
    const int gid = blockIdx.x * blockDim.x + threadIdx.x;
    for (int g = gid; g < NF8; g += T) {                  // x[N][64] f32 -> bf16, 8/thread
        const float4* s4 = (const float4*)x + (size_t)g * 2;
        float4 f0 = s4[0], f1 = s4[1];
        uint4 q;
        q.x = pk(f0.x, f0.y); q.y = pk(f0.z, f0.w);
        q.z = pk(f1.x, f1.y); q.w = pk(f1.z, f1.w);
        ((uint4*)xbf)[g] = q;
    }
    for (int g = gid; g < N; g += T) {                    // pn[g] = {pos.xyz, nrm.xyz, 0,0}
        float4 q0, q1;
        q0.x = pos[3*g]; q0.y = pos[3*g+1]; q0.z = pos[3*g+2]; q0.w = normal[3*g];
        q1.x = normal[3*g+1]; q1.y = normal[3*g+2]; q1.z = 0.f; q1.w = 0.f;
        ((float4*)pn)[(size_t)g * 2]     = q0;
        ((float4*)pn)[(size_t)g * 2 + 1] = q1;
    }
    for (int g = gid; g < H_DIM * LW2; g += T) {          // W rows 64..131 -> [H][LW2]
        int h = g / LW2, k = g % LW2;
        float v = 0.f;
        if (k < F_DIM)          v = W[(F_DIM + k) * H_DIM + h];
        else if (k < F_DIM + 4) v = W[(2 * F_DIM + (k - F_DIM)) * H_DIM + h];
        wt2[g] = f2bf(v);
    }
    for (int g = gid; g < H_DIM * LW1; g += T) {          // W rows 0..63 -> [H][LW1]
        int h = g / LW1, k = g % LW1;
        w1t[g] = f2bf((k < F_DIM) ? W[k * H_DIM + h] : 0.f);
    }
    for (int g = gid; g < S; g += T) node2slot[idx[g]] = g;  // any winner = canonical slot
    for (int g = gid; g < 3 * S; g += T)                     // out tail = pos[idx]
        out[(size_t)S * H_DIM + g] = pos[(size_t)idx[g / 3] * 3 + (g % 3)];
}

// block-local LDS histogram (fast atomics, return = local rank), then dump counts row.
// Stable counting sort phase 1. Also zeroes the scan total (frees a memset dispatch).
__global__ __launch_bounds__(1024)
void hist_kernel(const int* __restrict__ edge, const int* __restrict__ node2slot,
                 unsigned short* __restrict__ rank16, int* __restrict__ counts,
                 int* __restrict__ total, int E, int S, int chunk) {
    __shared__ int hcnt[SMAX];
    if (blockIdx.x == 0 && threadIdx.x == 0) *total = 0;
    for (int i = threadIdx.x; i < S; i += 1024) hcnt[i] = 0;
    __syncthreads();
    const int base = blockIdx.x * chunk;
    int end = base + chunk; if (end > E) end = E;
    for (int e = base + (int)threadIdx.x; e < end; e += 1024) {
        int s = node2slot[edge[E + e]];     // every e1 is sampled -> canonical slot
        rank16[e] = (unsigned short)atomicAdd(&hcnt[s], 1);
    }
    __syncthreads();
    int* crow = counts + (size_t)blockIdx.x * S;
    for (int i = threadIdx.x; i < S; i += 1024) crow[i] = hcnt[i];
}

// blocks [0,AB): counting-sort phase 2 fused with slot-prefix -> per-block bases, nseg,
// off. blocks [AB,AB+CB): cmat = b + x[idx]·W1 -> out
__global__ __launch_bounds__(256)
void alloc_cmat(int* __restrict__ counts, int* __restrict__ nseg,
                int* __restrict__ off, int* __restrict__ total,
                const unsigned short* __restrict__ xbf,
                const unsigned short* __restrict__ w1t, const float* __restrict__ bias,
                const int* __restrict__ idx, float* __restrict__ out, int S, int AB) {
    __shared__ int wsum[4];
    __shared__ int bb;
    __shared__ __align__(16) unsigned short a_lds[64 * LW1];
    const int tid = threadIdx.x;

    if ((int)blockIdx.x < AB) {
        int s = blockIdx.x * 256 + tid;
        int v = 0;
        if (s < S) {
            int acc = 0;
            for (int b2 = 0; b2 < NB; ++b2) {       // column scan (coalesced across tid)
                size_t o = (size_t)b2 * S + s;
                int c = counts[o];
                counts[o] = acc;
                acc += c;
            }
            nseg[s] = acc;                           // dup slots get 0 automatically
            v = acc;
        }
        int lane = tid & 63, wv = tid >> 6;
        int sc = v;
        #pragma unroll
        for (int d = 1; d < 64; d <<= 1) {
            int t = __shfl_up(sc, d, 64);
            if (lane >= d) sc += t;
        }
        if (lane == 63) wsum[wv] = sc;
        __syncthreads();
        if (tid == 0) {
            int t = 0;
            #pragma unroll
            for (int i = 0; i < 4; ++i) { int w = wsum[i]; wsum[i] = t; t += w; }
            bb = atomicAdd(total, t);
        }
        __syncthreads();
        int excl = bb + wsum[wv] + sc - v;
        if (s < S) off[s] = excl;
        return;
    }

    // ---- cmat: 64 slots per block, A rows from xbf (already bf16) ----
    const int sbase = (blockIdx.x - AB) * 64;
    const int m = tid >> 2, p = tid & 3;
    {
        int s = sbase + m; if (s >= S) s = S - 1;
        int node = idx[s];
        const uint4* src = (const uint4*)(xbf + (size_t)node * F_DIM) + p * 2;
        uint4* dst = (uint4*)(a_lds + m * LW1 + p * 16);
        dst[0] = src[0]; dst[1] = src[1];
        if (p == 0) *(uint4*)(a_lds + m * LW1 + 64) = make_uint4(0, 0, 0, 0);
    }
    __syncthreads();
    const int wv = tid >> 6, lane = tid & 63, l15 = lane & 15, quad = lane >> 4;
    const int n0 = wv * 32 + l15, n1 = n0 + 16;
    f32x4 acc[4][2];
    #pragma unroll
    for (int i = 0; i < 4; ++i) {
        acc[i][0] = (f32x4){0.f, 0.f, 0.f, 0.f};
        acc[i][1] = (f32x4){0.f, 0.f, 0.f, 0.f};
    }
    #pragma unroll
    for (int ks = 0; ks < 2; ++ks) {
        const int ko = ks * 32 + quad * 8;
        short8 bf0 = *(const short8*)(w1t + (size_t)n0 * LW1 + ko);
        short8 bf1 = *(const short8*)(w1t + (size_t)n1 * LW1 + ko);
        #pragma unroll
        for (int mt = 0; mt < 4; ++mt) {
            short8 af = *(const short8*)(a_lds + (mt * 16 + l15) * LW1 + ko);
            acc[mt][0] = __builtin_amdgcn_mfma_f32_16x16x32_bf16(af, bf0, acc[mt][0], 0, 0, 0);
            acc[mt][1] = __builtin_amdgcn_mfma_f32_16x16x32_bf16(af, bf1, acc[mt][1], 0, 0, 0);
        }
    }
    const float b0 = bias[n0], b1 = bias[n1];
    #pragma unroll
    for (int mt = 0; mt < 4; ++mt) {
        #pragma unroll
        for (int r = 0; r < 4; ++r) {
            int s = sbase + mt * 16 + quad * 4 + r;     // C/D: row = quad*4 + reg
            if (s < S) {
                out[(size_t)s * H_DIM + n0] = acc[mt][0][r] + b0;
                out[(size_t)s * H_DIM + n1] = acc[mt][1][r] + b1;
            }
        }
    }
}

// threads [0,E): ATOMIC-FREE placement p = off[slot] + blockbase[b][slot] + localrank.
// Geometry gathers via packed pn (1 line/node instead of up to 4).
// threads [E,E+S): snfo[s] = {off[canonical(s)], n} so seg's startup is ONE 8B load.
__global__ void place_kernel(const int* __restrict__ edge, const float* __restrict__ pn,
                             const int* __restrict__ node2slot,
                             const unsigned short* __restrict__ rank16,
                             const int* __restrict__ off, const int* __restrict__ counts,
                             const int* __restrict__ nseg, const int* __restrict__ idx,
                             uint4* __restrict__ prec, int2* __restrict__ snfo,
                             int E, int S, int chunk) {
    int g = blockIdx.x * blockDim.x + threadIdx.x;
    if (g >= E) {
        int s = g - E;
        if (s < S) {
            int sp = node2slot[idx[s]];
            snfo[s] = make_int2(off[sp], nseg[sp]);
        }
        return;
    }
    int e0 = edge[g], e1 = edge[E + g];
    int slot = node2slot[e1];
    int b = g / chunk;
    int p = off[slot] + counts[(size_t)b * S + slot] + (int)rank16[g];
    const float4* pn4 = (const float4*)pn;
    float4 p0a = pn4[(size_t)e0 * 2], p0b = pn4[(size_t)e0 * 2 + 1];
    float4 p1a = pn4[(size_t)e1 * 2], p1b = pn4[(size_t)e1 * 2 + 1];
    float px = p0a.x - p1a.x;
    float py = p0a.y - p1a.y;
    float pz = p0a.z - p1a.z;
    float n0x = p0a.w, n0y = p0b.x, n0z = p0b.y;
    float n1x = p1a.w, n1y = p1b.x, n1z = p1b.y;
    float d  = sqrtf(px * px + py * py + pz * pz);
    float a1 = angle3(n1x, n1y, n1z, px, py, pz);
    float a2 = angle3(n0x, n0y, n0z, px, py, pz);
    float a3 = angle3(n1x, n1y, n1z, n0x, n0y, n0z);
    uint4 rec;
    rec.x = (unsigned)e0;
    rec.y = pk(d, a1);
    rec.z = pk(a2, a3);
    rec.w = 0;
    prec[p] = rec;
}

__device__ __forceinline__ void load_af(uint4 rec, const unsigned short* __restrict__ xbf,
                                        int quad, short8& a0, short8& a1, short8& a2) {
    const short8* xr = (const short8*)(xbf + (size_t)rec.x * F_DIM);
    a0 = xr[quad];          // k = quad*8 .. +8
    a1 = xr[4 + quad];      // k = 32 + quad*8 .. +8
    short8 z = (short8){0, 0, 0, 0, 0, 0, 0, 0};
    if (quad == 0) {        // k = 64..67 = ppf, 68..71 zero (wt2 rows 68+ are zero anyway)
        z[0] = (short)(rec.y & 0xffff); z[1] = (short)(rec.y >> 16);
        z[2] = (short)(rec.z & 0xffff); z[3] = (short)(rec.z >> 16);
    }
    a2 = z;
}

// wave-per-segment with SEGMENT-LEVEL software pipeline (R13: per-segment startup
// chain snfo->rec->A was the binding latency, not the within-tile hops). Carried
// state: nf (current snfo, resident), rec_c (current tile-0 record, resident),
// a*c (current tile-0 A-frags, in flight), nf_nx (next snfo, in flight). Each loop
// body issues depth-2 snfo + next-seg rec during current MFMAs, and next-seg A-frags
// during the reduce/write. Epilogue orow operands prefetched at segment start.
// STATIC interleave (R9: central queue = serialized atomics). __launch_bounds__(256,2):
// the only clean regalloc regime (R6+R8: waves/EU=4 caps VGPR at 64 -> spills).
__global__ __launch_bounds__(256, 2)
void seg_kernel(const unsigned short* __restrict__ xbf, const unsigned short* __restrict__ wt2,
                const uint4* __restrict__ prec, const int2* __restrict__ snfo,
                float* __restrict__ out, int S) {
    __shared__ __align__(16) unsigned short w_lds[H_DIM * LW2];
    {
        const uint4* src = (const uint4*)wt2;
        uint4* dst = (uint4*)w_lds;
        for (int g = threadIdx.x; g < H_DIM * LW2 / 8; g += 256) dst[g] = src[g];
    }
    __syncthreads();

    const int tid  = threadIdx.x;
    const int wv   = tid >> 6;
    const int lane = tid & 63;
    const int l15  = lane & 15;
    const int quad = lane >> 4;
    const int nw   = gridDim.x << 2;

    int s = (blockIdx.x << 2) + wv;
    if (s >= S) return;

    // pipeline prologue (one-time exposed latency)
    int2 nf = snfo[s];
    uint4 rec_c = make_uint4(0, 0, 0, 0);
    if (nf.y > 0) rec_c = prec[nf.x + (l15 < nf.y ? l15 : nf.y - 1)];
    short8 a0c, a1c, a2c;
    load_af(rec_c, xbf, quad, a0c, a1c, a2c);
    int2 nf_nx = make_int2(0, 0);
    if (s + nw < S) nf_nx = snfo[s + nw];

    while (true) {
        const int s2 = s + nw;
        const int n  = nf.y;
        float* orow = out + (size_t)s * H_DIM;

        // issue next-iteration prefetches (overlap current segment's compute)
        int2 nf_nx2 = make_int2(0, 0);
        if (s2 + nw < S) nf_nx2 = snfo[s2 + nw];          // depth-2 snfo, independent
        uint4 rec_c2 = make_uint4(0, 0, 0, 0);
        if (s2 < S && nf_nx.y > 0)                        // nf_nx resident -> issues now
            rec_c2 = prec[nf_nx.x + (l15 < nf_nx.y ? l15 : nf_nx.y - 1)];

        if (n == 0) {                   // empty segment -> 0 (reference isfinite fixup)
            orow[lane] = 0.f;
            orow[64 + lane] = 0.f;
            load_af(rec_c2, xbf, quad, a0c, a1c, a2c);    // keep pipeline primed
        } else {
            float c0 = orow[lane], c1 = orow[64 + lane];  // epilogue operand prefetch
            const uint4* pb = prec + nf.x;

            float rm[8];
            #pragma unroll
            for (int ct = 0; ct < 8; ++ct) rm[ct] = -FLT_MAX;

            const int ntile = (n + 15) >> 4;
            uint4 rec_n = rec_c;
            if (ntile > 1) { int r1 = 16 + l15; if (r1 >= n) r1 = n - 1; rec_n = pb[r1]; }

            for (int t = 0; t < ntile; ++t) {
                uint4 rec_nn = rec_n;
                if (t + 2 < ntile) {
                    int rn = ((t + 2) << 4) + l15; if (rn >= n) rn = n - 1;
                    rec_nn = pb[rn];
                }
                short8 a0n, a1n, a2n;
                load_af(rec_n, xbf, quad, a0n, a1n, a2n);

                f32x4 acc[8];
                #pragma unroll
                for (int ct = 0; ct < 8; ++ct) acc[ct] = (f32x4){0.f, 0.f, 0.f, 0.f};
                #pragma unroll
                for (int ct = 0; ct < 8; ++ct) {
                    const unsigned short* wc = w_lds + (ct * 16 + l15) * LW2 + (quad << 3);
                    short8 b0 = *(const short8*)(wc);
                    short8 b1 = *(const short8*)(wc + 32);
                    short8 b2 = *(const short8*)(wc + 64);
                    acc[ct] = __builtin_amdgcn_mfma_f32_16x16x32_bf16(a0c, b0, acc[ct], 0, 0, 0);
                    acc[ct] = __builtin_amdgcn_mfma_f32_16x16x32_bf16(a1c, b1, acc[ct], 0, 0, 0);
                    acc[ct] = __builtin_amdgcn_mfma_f32_16x16x32_bf16(a2c, b2, acc[ct], 0, 0, 0);
                }
                #pragma unroll
                for (int ct = 0; ct < 8; ++ct)
                    rm[ct] = fmaxf(rm[ct], fmaxf(fmaxf(acc[ct][0], acc[ct][1]),
                                                 fmaxf(acc[ct][2], acc[ct][3])));
                a0c = a0n; a1c = a1n; a2c = a2n;
                rec_n = rec_nn;
            }

            // issue next segment's A-frags (rec_c2 resident by now); overlaps reduce
            short8 a0x, a1x, a2x;
            load_af(rec_c2, xbf, quad, a0x, a1x, a2x);

            #pragma unroll
            for (int ct = 0; ct < 8; ++ct) {
                rm[ct] = fmaxf(rm[ct], __shfl_xor(rm[ct], 16, 64));
                rm[ct] = fmaxf(rm[ct], __shfl_xor(rm[ct], 32, 64));
            }
            float v0 = rm[0], v1 = rm[4];   // col = ct*16 + l15; lane -> cols lane, lane+64
            if (quad == 1)      { v0 = rm[1]; v1 = rm[5]; }
            else if (quad == 2) { v0 = rm[2]; v1 = rm[6]; }
            else if (quad == 3) { v0 = rm[3]; v1 = rm[7]; }
            orow[lane]      = fmaxf(c0 + v0, 0.f);        // c + max, relu (hoist exact)
            orow[64 + lane] = fmaxf(c1 + v1, 0.f);

            a0c = a0x; a1c = a1x; a2c = a2x;
        }

        if (s2 >= S) break;
        rec_c = rec_c2;
        nf = nf_nx;
        nf_nx = nf_nx2;
        s = s2;
    }
}

extern "C" void kernel_launch(void* const* d_in, const int* in_sizes, int n_in,
                              void* d_out, int out_size, void* d_ws, size_t ws_size,
                              hipStream_t stream) {
    const float* x      = (const float*)d_in[0];
    const float* pos    = (const float*)d_in[1];
    const float* normal = (const float*)d_in[2];
    const float* W      = (const float*)d_in[3];
    const float* b      = (const float*)d_in[4];
    const int*   edge   = (const int*)d_in[5];
    const int*   idx    = (const int*)d_in[6];

    const int H = in_sizes[4];            // 128
    const int K = in_sizes[3] / H;        // 132
    const int F = (K - 4) / 2;            // 64
    const int N = in_sizes[0] / F;        // 100000
    const int E = in_sizes[5] / 2;        // 800000
    const int S = in_sizes[6];            // 25000  (SMAX=25600 LDS histogram bound)

    // ws (256B aligned): wt2 | w1t | xbf[N*64]bf16 | pn[N*8]f32 | prec[E]uint4
    //                    | node2slot[N] | rank16[E] | counts[NB*S] | nseg[S] | off[S]
    //                    | snfo[S] | total
    char* p = (char*)d_ws;
    auto alloc = [&](size_t bytes) { char* r = p; p += (bytes + 255) & ~(size_t)255; return r; };
    unsigned short* wt2 = (unsigned short*)alloc((size_t)H_DIM * LW2 * sizeof(unsigned short));
    unsigned short* w1t = (unsigned short*)alloc((size_t)H_DIM * LW1 * sizeof(unsigned short));
    unsigned short* xbf = (unsigned short*)alloc((size_t)N * F_DIM * sizeof(unsigned short));
    float* pn           = (float*)alloc((size_t)N * 8 * sizeof(float));
    uint4* prec         = (uint4*)alloc((size_t)E * sizeof(uint4));
    int* node2slot      = (int*)alloc((size_t)N * sizeof(int));
    unsigned short* rank16 = (unsigned short*)alloc((size_t)E * sizeof(unsigned short));
    int* counts         = (int*)alloc((size_t)NB * S * sizeof(int));
    int* nseg           = (int*)alloc((size_t)S * sizeof(int));
    int* off            = (int*)alloc((size_t)S * sizeof(int));
    int2* snfo          = (int2*)alloc((size_t)S * sizeof(int2));
    int* total          = (int*)alloc(sizeof(int));
    float* out = (float*)d_out;           // cmat writes c, seg RMWs to final result

    const int AB = (S + 255) / 256;
    const int CB = (S + 63) / 64;
    const int NF8 = N * F_DIM / 8;
    const int chunk = (E + NB - 1) / NB;  // 6250 (< 65536: rank16 fits u16)

    prep0<<<2048, 256, 0, stream>>>(W, wt2, w1t, x, xbf, idx, node2slot, pos, normal,
                                    pn, out, N, S, NF8);
    hist_kernel<<<NB, 1024, 0, stream>>>(edge, node2slot, rank16, counts, total, E, S, chunk);
    alloc_cmat<<<AB + CB, 256, 0, stream>>>(counts, nseg, off, total, xbf, w1t, b,
                                            idx, out, S, AB);
    place_kernel<<<(E + S + 255) / 256, 256, 0, stream>>>(edge, pn, node2slot, rank16,
                                                          off, counts, nseg, idx,
                                                          prec, snfo, E, S, chunk);
    seg_kernel<<<2048, 256, 0, stream>>>(xbf, wt2, prec, snfo, out, S);
}

// Round 15
// 206.767 us; speedup vs baseline: 1.0561x; 1.0561x over previous
//
#include <hip/hip_runtime.h>
#include <hip/hip_bf16.h>
#include <float.h>

#define F_DIM 64
#define H_DIM 128
#define LW2   104   // wt2 row stride (bf16) for K=96 [x[e0]|ppf|pad]: 208 B, 16B-aligned
#define LW1   72    // w1t row stride (bf16) for K=64 [x[e1]]: 144 B, 16B-aligned
#define NB    128   // histogram blocks (counting-sort partitions)
#define SB    128   // streaming-role blocks fused into histx (idle half of the chip)
#define SMAX  25600 // max slots supported by the LDS histogram (100 KB of 160 KB/CU)

typedef __attribute__((ext_vector_type(8))) short short8;   // 8 bf16 (mfma A/B frag)
typedef __attribute__((ext_vector_type(4))) float f32x4;    // mfma C/D frag

__device__ __forceinline__ unsigned short f2bf(float f) {
    __hip_bfloat16 h = __float2bfloat16(f);
    return __builtin_bit_cast(unsigned short, h);
}
__device__ __forceinline__ unsigned pk(float a, float b) {
    return (unsigned)f2bf(a) | ((unsigned)f2bf(b) << 16);
}

__device__ __forceinline__ float angle3(float ax, float ay, float az,
                                        float bx, float by, float bz) {
    float cx = ay*bz - az*by;
    float cy = az*bx - ax*bz;
    float cz = ax*by - ay*bx;
    float cn = sqrtf(cx*cx + cy*cy + cz*cz);
    float d  = ax*bx + ay*by + az*bz;
    return atan2f(cn, d);
}

// tiny prerequisite pass: only what hist needs (node2slot) + small builds.
// The big streams (xbf, pn) moved into histx's streaming-role blocks.
__global__ __launch_bounds__(256)
void prep_tiny(const float* __restrict__ W, unsigned short* __restrict__ wt2,
               unsigned short* __restrict__ w1t, const int* __restrict__ idx,
               int* __restrict__ node2slot, const float* __restrict__ pos,
               float* __restrict__ out, int S) {
    const int T = gridDim.x * blockDim.x;
    const int gid = blockIdx.x * blockDim.x + threadIdx.x;
    for (int g = gid; g < H_DIM * LW2; g += T) {          // W rows 64..131 -> [H][LW2]
        int h = g / LW2, k = g % LW2;
        float v = 0.f;
        if (k < F_DIM)          v = W[(F_DIM + k) * H_DIM + h];
        else if (k < F_DIM + 4) v = W[(2 * F_DIM + (k - F_DIM)) * H_DIM + h];
        wt2[g] = f2bf(v);
    }
    for (int g = gid; g < H_DIM * LW1; g += T) {          // W rows 0..63 -> [H][LW1]
        int h = g / LW1, k = g % LW1;
        w1t[g] = f2bf((k < F_DIM) ? W[k * H_DIM + h] : 0.f);
    }
    for (int g = gid; g < S; g += T) node2slot[idx[g]] = g;  // any winner = canonical slot
    for (int g = gid; g < 3 * S; g += T)                     // out tail = pos[idx]
        out[(size_t)S * H_DIM + g] = pos[(size_t)idx[g / 3] * 3 + (g % 3)];
}

// role-split kernel: blocks [0,NB) = block-local LDS histogram (fast atomics, return =
// local rank -> stable counting sort phase 1); blocks [NB,NB+SB) = streaming (xbf
// conversion + pn packing) on the OTHERWISE-IDLE half of the chip (hist's 100KB LDS
// caps it at 1 block/CU, 128 blocks = 128 CUs; streaming rides the other 128).
__global__ __launch_bounds__(1024)
void histx(const int* __restrict__ edge, const int* __restrict__ node2slot,
           unsigned short* __restrict__ rank16, int* __restrict__ counts,
           int* __restrict__ total, const float* __restrict__ x,
           unsigned short* __restrict__ xbf, const float* __restrict__ pos,
           const float* __restrict__ normal, float* __restrict__ pn,
           int E, int S, int chunk, int N, int NF8) {
    __shared__ int hcnt[SMAX];
    if ((int)blockIdx.x >= NB) {
        // ---- streaming role ----
        const int T2 = SB * 1024;
        const int g0 = (blockIdx.x - NB) * 1024 + threadIdx.x;
        for (int g = g0; g < NF8; g += T2) {              // x[N][64] f32 -> bf16, 8/thread
            const float4* s4 = (const float4*)x + (size_t)g * 2;
            float4 f0 = s4[0], f1 = s4[1];
            uint4 q;
            q.x = pk(f0.x, f0.y); q.y = pk(f0.z, f0.w);
            q.z = pk(f1.x, f1.y); q.w = pk(f1.z, f1.w);
            ((uint4*)xbf)[g] = q;
        }
        for (int g = g0; g < N; g += T2) {                // pn[g] = {pos.xyz, nrm.xyz,0,0}
            float4 q0, q1;
            q0.x = pos[3*g]; q0.y = pos[3*g+1]; q0.z = pos[3*g+2]; q0.w = normal[3*g];
            q1.x = normal[3*g+1]; q1.y = normal[3*g+2]; q1.z = 0.f; q1.w = 0.f;
            ((float4*)pn)[(size_t)g * 2]     = q0;
            ((float4*)pn)[(size_t)g * 2 + 1] = q1;
        }
        return;
    }
    // ---- histogram role ----
    if (blockIdx.x == 0 && threadIdx.x == 0) *total = 0;
    for (int i = threadIdx.x; i < S; i += 1024) hcnt[i] = 0;
    __syncthreads();
    const int base = blockIdx.x * chunk;
    int end = base + chunk; if (end > E) end = E;
    for (int e = base + (int)threadIdx.x; e < end; e += 1024) {
        int s = node2slot[edge[E + e]];     // every e1 is sampled -> canonical slot
        rank16[e] = (unsigned short)atomicAdd(&hcnt[s], 1);
    }
    __syncthreads();
    int* crow = counts + (size_t)blockIdx.x * S;
    for (int i = threadIdx.x; i < S; i += 1024) crow[i] = hcnt[i];
}

// blocks [0,AB): counting-sort phase 2 fused with slot-prefix -> per-block bases, nseg,
// off. blocks [AB,AB+CB): cmat = b + x[idx]·W1 -> out
__global__ __launch_bounds__(256)
void alloc_cmat(int* __restrict__ counts, int* __restrict__ nseg,
                int* __restrict__ off, int* __restrict__ total,
                const unsigned short* __restrict__ xbf,
                const unsigned short* __restrict__ w1t, const float* __restrict__ bias,
                const int* __restrict__ idx, float* __restrict__ out, int S, int AB) {
    __shared__ int wsum[4];
    __shared__ int bb;
    __shared__ __align__(16) unsigned short a_lds[64 * LW1];
    const int tid = threadIdx.x;

    if ((int)blockIdx.x < AB) {
        int s = blockIdx.x * 256 + tid;
        int v = 0;
        if (s < S) {
            int acc = 0;
            for (int b2 = 0; b2 < NB; ++b2) {       // column scan (coalesced across tid)
                size_t o = (size_t)b2 * S + s;
                int c = counts[o];
                counts[o] = acc;
                acc += c;
            }
            nseg[s] = acc;                           // dup slots get 0 automatically
            v = acc;
        }
        int lane = tid & 63, wv = tid >> 6;
        int sc = v;
        #pragma unroll
        for (int d = 1; d < 64; d <<= 1) {
            int t = __shfl_up(sc, d, 64);
            if (lane >= d) sc += t;
        }
        if (lane == 63) wsum[wv] = sc;
        __syncthreads();
        if (tid == 0) {
            int t = 0;
            #pragma unroll
            for (int i = 0; i < 4; ++i) { int w = wsum[i]; wsum[i] = t; t += w; }
            bb = atomicAdd(total, t);
        }
        __syncthreads();
        int excl = bb + wsum[wv] + sc - v;
        if (s < S) off[s] = excl;
        return;
    }

    // ---- cmat: 64 slots per block, A rows from xbf (already bf16) ----
    const int sbase = (blockIdx.x - AB) * 64;
    const int m = tid >> 2, p = tid & 3;
    {
        int s = sbase + m; if (s >= S) s = S - 1;
        int node = idx[s];
        const uint4* src = (const uint4*)(xbf + (size_t)node * F_DIM) + p * 2;
        uint4* dst = (uint4*)(a_lds + m * LW1 + p * 16);
        dst[0] = src[0]; dst[1] = src[1];
        if (p == 0) *(uint4*)(a_lds + m * LW1 + 64) = make_uint4(0, 0, 0, 0);
    }
    __syncthreads();
    const int wv = tid >> 6, lane = tid & 63, l15 = lane & 15, quad = lane >> 4;
    const int n0 = wv * 32 + l15, n1 = n0 + 16;
    f32x4 acc[4][2];
    #pragma unroll
    for (int i = 0; i < 4; ++i) {
        acc[i][0] = (f32x4){0.f, 0.f, 0.f, 0.f};
        acc[i][1] = (f32x4){0.f, 0.f, 0.f, 0.f};
    }
    #pragma unroll
    for (int ks = 0; ks < 2; ++ks) {
        const int ko = ks * 32 + quad * 8;
        short8 bf0 = *(const short8*)(w1t + (size_t)n0 * LW1 + ko);
        short8 bf1 = *(const short8*)(w1t + (size_t)n1 * LW1 + ko);
        #pragma unroll
        for (int mt = 0; mt < 4; ++mt) {
            short8 af = *(const short8*)(a_lds + (mt * 16 + l15) * LW1 + ko);
            acc[mt][0] = __builtin_amdgcn_mfma_f32_16x16x32_bf16(af, bf0, acc[mt][0], 0, 0, 0);
            acc[mt][1] = __builtin_amdgcn_mfma_f32_16x16x32_bf16(af, bf1, acc[mt][1], 0, 0, 0);
        }
    }
    const float b0 = bias[n0], b1 = bias[n1];
    #pragma unroll
    for (int mt = 0; mt < 4; ++mt) {
        #pragma unroll
        for (int r = 0; r < 4; ++r) {
            int s = sbase + mt * 16 + quad * 4 + r;     // C/D: row = quad*4 + reg
            if (s < S) {
                out[(size_t)s * H_DIM + n0] = acc[mt][0][r] + b0;
                out[(size_t)s * H_DIM + n1] = acc[mt][1][r] + b1;
            }
        }
    }
}

// threads [0,E): ATOMIC-FREE placement p = off[slot] + blockbase[b][slot] + localrank.
// Geometry gathers via packed pn (1 line/node instead of up to 4).
// threads [E,E+S): snfo[s] = {off[canonical(s)], n} so seg's startup is ONE 8B load.
__global__ void place_kernel(const int* __restrict__ edge, const float* __restrict__ pn,
                             const int* __restrict__ node2slot,
                             const unsigned short* __restrict__ rank16,
                             const int* __restrict__ off, const int* __restrict__ counts,
                             const int* __restrict__ nseg, const int* __restrict__ idx,
                             uint4* __restrict__ prec, int2* __restrict__ snfo,
                             int E, int S, int chunk) {
    int g = blockIdx.x * blockDim.x + threadIdx.x;
    if (g >= E) {
        int s = g - E;
        if (s < S) {
            int sp = node2slot[idx[s]];
            snfo[s] = make_int2(off[sp], nseg[sp]);
        }
        return;
    }
    int e0 = edge[g], e1 = edge[E + g];
    int slot = node2slot[e1];
    int b = g / chunk;
    int p = off[slot] + counts[(size_t)b * S + slot] + (int)rank16[g];
    const float4* pn4 = (const float4*)pn;
    float4 p0a = pn4[(size_t)e0 * 2], p0b = pn4[(size_t)e0 * 2 + 1];
    float4 p1a = pn4[(size_t)e1 * 2], p1b = pn4[(size_t)e1 * 2 + 1];
    float px = p0a.x - p1a.x;
    float py = p0a.y - p1a.y;
    float pz = p0a.z - p1a.z;
    float n0x = p0a.w, n0y = p0b.x, n0z = p0b.y;
    float n1x = p1a.w, n1y = p1b.x, n1z = p1b.y;
    float d  = sqrtf(px * px + py * py + pz * pz);
    float a1 = angle3(n1x, n1y, n1z, px, py, pz);
    float a2 = angle3(n0x, n0y, n0z, px, py, pz);
    float a3 = angle3(n1x, n1y, n1z, n0x, n0y, n0z);
    uint4 rec;
    rec.x = (unsigned)e0;
    rec.y = pk(d, a1);
    rec.z = pk(a2, a3);
    rec.w = 0;
    prec[p] = rec;
}

__device__ __forceinline__ void load_af(uint4 rec, const unsigned short* __restrict__ xbf,
                                        int quad, short8& a0, short8& a1, short8& a2) {
    const short8* xr = (const short8*)(xbf + (size_t)rec.x * F_DIM);
    a0 = xr[quad];          // k = quad*8 .. +8
    a1 = xr[4 + quad];      // k = 32 + quad*8 .. +8
    short8 z = (short8){0, 0, 0, 0, 0, 0, 0, 0};
    if (quad == 0) {        // k = 64..67 = ppf, 68..71 zero (wt2 rows 68+ are zero anyway)
        z[0] = (short)(rec.y & 0xffff); z[1] = (short)(rec.y >> 16);
        z[2] = (short)(rec.z & 0xffff); z[3] = (short)(rec.z >> 16);
    }
    a2 = z;
}

// wave-per-segment, STATIC interleave; depth-2 record prefetch; snfo startup.
// EXACT R13 form — R14's segment-level pipeline regressed (VGPR 84->92, occ 22->17%,
// 56->61 µs): cross-segment carried state costs more regalloc than it hides latency.
// __launch_bounds__(256,2): the only clean regalloc regime (R6+R8: waves/EU=4 -> spill).
__global__ __launch_bounds__(256, 2)
void seg_kernel(const unsigned short* __restrict__ xbf, const unsigned short* __restrict__ wt2,
                const uint4* __restrict__ prec, const int2* __restrict__ snfo,
                float* __restrict__ out, int S) {
    __shared__ __align__(16) unsigned short w_lds[H_DIM * LW2];
    {
        const uint4* src = (const uint4*)wt2;
        uint4* dst = (uint4*)w_lds;
        for (int g = threadIdx.x; g < H_DIM * LW2 / 8; g += 256) dst[g] = src[g];
    }
    __syncthreads();

    const int tid  = threadIdx.x;
    const int wv   = tid >> 6;
    const int lane = tid & 63;
    const int l15  = lane & 15;
    const int quad = lane >> 4;
    const int nw   = gridDim.x << 2;

    for (int s = (blockIdx.x << 2) + wv; s < S; s += nw) {
        const int2 nf = snfo[s];
        const int n = nf.y;
        float* orow = out + (size_t)s * H_DIM;
        if (n == 0) {                   // empty segment -> 0 (reference isfinite fixup)
            orow[lane] = 0.f;
            orow[64 + lane] = 0.f;
            continue;
        }
        const uint4* pb = prec + nf.x;

        float rm[8];
        #pragma unroll
        for (int ct = 0; ct < 8; ++ct) rm[ct] = -FLT_MAX;

        const int ntile = (n + 15) >> 4;
        int r0 = l15;      if (r0 >= n) r0 = n - 1;   // pad rows = real dup -> exact for max
        int r1 = 16 + l15; if (r1 >= n) r1 = n - 1;
        uint4 rec_c = pb[r0];
        uint4 rec_n = (ntile > 1) ? pb[r1] : rec_c;
        short8 a0c, a1c, a2c;
        load_af(rec_c, xbf, quad, a0c, a1c, a2c);

        for (int t = 0; t < ntile; ++t) {
            // rec two tiles ahead; A-frags one tile ahead from an already-resident rec
            uint4 rec_nn = rec_n;
            if (t + 2 < ntile) {
                int rn = ((t + 2) << 4) + l15; if (rn >= n) rn = n - 1;
                rec_nn = pb[rn];
            }
            short8 a0n, a1n, a2n;
            load_af(rec_n, xbf, quad, a0n, a1n, a2n);

            f32x4 acc[8];
            #pragma unroll
            for (int ct = 0; ct < 8; ++ct) acc[ct] = (f32x4){0.f, 0.f, 0.f, 0.f};
            #pragma unroll
            for (int ct = 0; ct < 8; ++ct) {
                const unsigned short* wc = w_lds + (ct * 16 + l15) * LW2 + (quad << 3);
                short8 b0 = *(const short8*)(wc);
                short8 b1 = *(const short8*)(wc + 32);
                short8 b2 = *(const short8*)(wc + 64);
                acc[ct] = __builtin_amdgcn_mfma_f32_16x16x32_bf16(a0c, b0, acc[ct], 0, 0, 0);
                acc[ct] = __builtin_amdgcn_mfma_f32_16x16x32_bf16(a1c, b1, acc[ct], 0, 0, 0);
                acc[ct] = __builtin_amdgcn_mfma_f32_16x16x32_bf16(a2c, b2, acc[ct], 0, 0, 0);
            }
            #pragma unroll
            for (int ct = 0; ct < 8; ++ct)
                rm[ct] = fmaxf(rm[ct], fmaxf(fmaxf(acc[ct][0], acc[ct][1]),
                                             fmaxf(acc[ct][2], acc[ct][3])));
            a0c = a0n; a1c = a1n; a2c = a2n;
            rec_n = rec_nn;
        }

        #pragma unroll
        for (int ct = 0; ct < 8; ++ct) {
            rm[ct] = fmaxf(rm[ct], __shfl_xor(rm[ct], 16, 64));
            rm[ct] = fmaxf(rm[ct], __shfl_xor(rm[ct], 32, 64));
        }
        float v0 = rm[0], v1 = rm[4];   // col = ct*16 + l15; lane -> cols lane, lane+64
        if (quad == 1)      { v0 = rm[1]; v1 = rm[5]; }
        else if (quad == 2) { v0 = rm[2]; v1 = rm[6]; }
        else if (quad == 3) { v0 = rm[3]; v1 = rm[7]; }
        orow[lane]      = fmaxf(orow[lane] + v0, 0.f);    // c + max, relu (hoist exact)
        orow[64 + lane] = fmaxf(orow[64 + lane] + v1, 0.f);
    }
}

extern "C" void kernel_launch(void* const* d_in, const int* in_sizes, int n_in,
                              void* d_out, int out_size, void* d_ws, size_t ws_size,
                              hipStream_t stream) {
    const float* x      = (const float*)d_in[0];
    const float* pos    = (const float*)d_in[1];
    const float* normal = (const float*)d_in[2];
    const float* W      = (const float*)d_in[3];
    const float* b      = (const float*)d_in[4];
    const int*   edge   = (const int*)d_in[5];
    const int*   idx    = (const int*)d_in[6];

    const int H = in_sizes[4];            // 128
    const int K = in_sizes[3] / H;        // 132
    const int F = (K - 4) / 2;            // 64
    const int N = in_sizes[0] / F;        // 100000
    const int E = in_sizes[5] / 2;        // 800000
    const int S = in_sizes[6];            // 25000  (SMAX=25600 LDS histogram bound)

    // ws (256B aligned): wt2 | w1t | xbf[N*64]bf16 | pn[N*8]f32 | prec[E]uint4
    //                    | node2slot[N] | rank16[E] | counts[NB*S] | nseg[S] | off[S]
    //                    | snfo[S] | total
    char* p = (char*)d_ws;
    auto alloc = [&](size_t bytes) { char* r = p; p += (bytes + 255) & ~(size_t)255; return r; };
    unsigned short* wt2 = (unsigned short*)alloc((size_t)H_DIM * LW2 * sizeof(unsigned short));
    unsigned short* w1t = (unsigned short*)alloc((size_t)H_DIM * LW1 * sizeof(unsigned short));
    unsigned short* xbf = (unsigned short*)alloc((size_t)N * F_DIM * sizeof(unsigned short));
    float* pn           = (float*)alloc((size_t)N * 8 * sizeof(float));
    uint4* prec         = (uint4*)alloc((size_t)E * sizeof(uint4));
    int* node2slot      = (int*)alloc((size_t)N * sizeof(int));
    unsigned short* rank16 = (unsigned short*)alloc((size_t)E * sizeof(unsigned short));
    int* counts         = (int*)alloc((size_t)NB * S * sizeof(int));
    int* nseg           = (int*)alloc((size_t)S * sizeof(int));
    int* off            = (int*)alloc((size_t)S * sizeof(int));
    int2* snfo          = (int2*)alloc((size_t)S * sizeof(int2));
    int* total          = (int*)alloc(sizeof(int));
    float* out = (float*)d_out;           // cmat writes c, seg RMWs to final result

    const int AB = (S + 255) / 256;
    const int CB = (S + 63) / 64;
    const int NF8 = N * F_DIM / 8;
    const int chunk = (E + NB - 1) / NB;  // 6250 (< 65536: rank16 fits u16)

    prep_tiny<<<512, 256, 0, stream>>>(W, wt2, w1t, idx, node2slot, pos, out, S);
    histx<<<NB + SB, 1024, 0, stream>>>(edge, node2slot, rank16, counts, total,
                                        x, xbf, pos, normal, pn, E, S, chunk, N, NF8);
    alloc_cmat<<<AB + CB, 256, 0, stream>>>(counts, nseg, off, total, xbf, w1t, b,
                                            idx, out, S, AB);
    place_kernel<<<(E + S + 255) / 256, 256, 0, stream>>>(edge, pn, node2slot, rank16,
                                                          off, counts, nseg, idx,
                                                          prec, snfo, E, S, chunk);
    seg_kernel<<<2048, 256, 0, stream>>>(xbf, wt2, prec, snfo, out, S);
}